// Round 6
// baseline (553.889 us; speedup 1.0000x reference)
//
#include <hip/hip_runtime.h>
#include <math.h>

#define N_RES 8192
#define N_IN  128
#define BATCH 16
#define LEAK  0.9f

#define NBK    128     // buckets (row>>6), 64 rows each
#define CAP1B  55296   // per-bucket capacity (avg 53248, sigma~230, +8.9 sigma)
#define CHUNK1 4096    // pass1 entries per block (R5 post-mortem: 2048 doubled
                       //  block count -> per-block fixed costs + shorter e1
                       //  runs; 4096 geometry measured 65-68us vs 77-80us)
#define CHUNK2 4096    // pass2 entries per block (32KB stg, 512 thr -> 4 blocks/CU)
#define SB2    14      // ceil(CAP1B / CHUNK2) chunks per bucket
#define TBLK   128     // transpose blocks appended to pass1 grid

// Entry encoding: y = (row << 14) | col, row 13 bits, col 14 bits (0..8319).
//   bucket = y >> 20 (row>>6); local row rr = (y >> 14) & 63; col = y & 16383.

// ws layout (bytes):
//   srcT @ 0      : [8320][16] f32 transposed state|x   (532,480)
//   bcur @ 1 MiB  : int[128] counters, then int[128] done-flags (1 KB total)
//   z    @ 2 MiB  : [N_RES][BATCH] f32                  (524,288)
//   e1   @ 8 MiB  : uint2[NBK][CAP1B]                   (56,623,104)
// (R5: line-padding bcur was falsified -- no time change, +11MB HBM writes.)
#define OFF_SRCT 0
#define OFF_BCUR (1u << 20)
#define OFF_Z    (2u << 20)
#define OFF_E1   (8u << 20)
#define REQ_A    ((size_t)OFF_E1 + (size_t)NBK * CAP1B * 8)   // ~62 MiB

// ---------------------------------------------------------------------------
// K1: pass1 binning (blocks [0, nchunks)) + transpose/z-zero (blocks
// [nchunks, +TBLK)). bcur must be zeroed before launch. srcT and z are
// consumed only by pass2 (next dispatch) -> no intra-kernel ordering needed
// for the transpose section.
__global__ __launch_bounds__(256, 4) void pass1_fused(
    const float* __restrict__ state,   // [BATCH][N_RES]
    const float* __restrict__ x,       // [BATCH][N_IN]
    const float* __restrict__ vres, const int* __restrict__ rres,
    const int* __restrict__ cres, int nres, int nbres,
    const float* __restrict__ vin, const int* __restrict__ rin,
    const int* __restrict__ cin, int nin, int nchunks,
    float* __restrict__ srcT,          // [8320][16]
    float* __restrict__ z,             // [N_RES][BATCH] (zeroed here)
    uint2* __restrict__ e1,            // [NBK][CAP1B]
    int* __restrict__ bcur) {          // [NBK] (pre-zeroed)
  int tid = threadIdx.x;

  if (blockIdx.x >= nchunks) {         // ---- transpose + z-zero section ----
    int idx0 = (blockIdx.x - nchunks) * 256 + tid;
    const int stride = TBLK * 256;
    for (int i = idx0; i < N_RES * BATCH; i += stride) {
      int b = i >> 13;
      int r = i & (N_RES - 1);
      srcT[r * BATCH + b] = state[i];
      z[i] = 0.0f;
    }
    for (int i = idx0; i < N_IN * BATCH; i += stride) {
      int b = i >> 7;
      int c = i & (N_IN - 1);
      srcT[(N_RES + c) * BATCH + b] = x[i];
    }
    return;                            // block-uniform; no barriers used here
  }

  // ---- binning section ----
  const float* vals; const int* rows; const int* cols;
  int nnz, col_off, base;
  if (blockIdx.x < nbres) {
    vals = vres; rows = rres; cols = cres; nnz = nres; col_off = 0;
    base = blockIdx.x * CHUNK1;
  } else {
    vals = vin; rows = rin; cols = cin; nnz = nin; col_off = N_RES;
    base = (blockIdx.x - nbres) * CHUNK1;
  }

  __shared__ uint2 stg[CHUNK1];              // 32 KB
  __shared__ int hist[NBK];
  __shared__ int lbase[NBK];
  __shared__ int gbase[NBK];
  __shared__ int wsum[2];
  int wave = tid >> 6, lane = tid & 63;

  if (tid < NBK) hist[tid] = 0;
  __syncthreads();

  int n = nnz - base;
  if (n > CHUNK1) n = CHUNK1;

  uint2 ent[16];
  int lp[16];
  unsigned msk = 0;
#pragma unroll
  for (int g = 0; g < 4; ++g) {
    int i0 = (g * 256 + tid) * 4;            // 16B-aligned vector offset
    if (i0 + 3 < n) {
      int4 r4 = *(const int4*)(rows + base + i0);
      int4 c4 = *(const int4*)(cols + base + i0);
      float4 v4 = *(const float4*)(vals + base + i0);
      int rr_[4] = {r4.x, r4.y, r4.z, r4.w};
      int cc_[4] = {c4.x, c4.y, c4.z, c4.w};
      float vv_[4] = {v4.x, v4.y, v4.z, v4.w};
#pragma unroll
      for (int j = 0; j < 4; ++j) {
        int e = g * 4 + j;
        ent[e] = make_uint2(__float_as_uint(vv_[j]),
                            ((unsigned)rr_[j] << 14) |
                                (unsigned)(cc_[j] + col_off));
        msk |= 1u << e;
        lp[e] = atomicAdd(&hist[rr_[j] >> 6], 1);
      }
    } else {
#pragma unroll
      for (int j = 0; j < 4; ++j) {
        int e = g * 4 + j, i = i0 + j;
        if (i < n) {
          int r = rows[base + i];
          int c = cols[base + i] + col_off;
          float v = vals[base + i];
          ent[e] = make_uint2(__float_as_uint(v),
                              ((unsigned)r << 14) | (unsigned)c);
          msk |= 1u << e;
          lp[e] = atomicAdd(&hist[r >> 6], 1);
        }
      }
    }
  }
  __syncthreads();

  int h = 0, v = 0;
  if (tid < NBK) {                           // waves 0,1 scan 128 bins
    h = hist[tid];
    v = h;
#pragma unroll
    for (int d = 1; d < 64; d <<= 1) {
      int t = __shfl_up(v, d);
      if (lane >= d) v += t;
    }
    if (lane == 63) wsum[wave] = v;
  }
  __syncthreads();
  if (tid < NBK) {
    int off = (wave == 1) ? wsum[0] : 0;
    lbase[tid] = off + v - h;
    gbase[tid] = h ? atomicAdd(&bcur[tid], h) : 0;
  }
  __syncthreads();
#pragma unroll
  for (int e = 0; e < 16; ++e) {
    if (msk & (1u << e)) {
      int b = (int)(ent[e].y >> 20);         // recompute bin from packed row
      stg[lbase[b] + lp[e]] = ent[e];
    }
  }
  __syncthreads();
  for (int i = tid; i < n; i += 256) {
    uint2 ld = stg[i];
    int b = (int)(ld.y >> 20);
    int p = gbase[b] + (i - lbase[b]);
    if (p < CAP1B) e1[(size_t)b * CAP1B + p] = ld;
  }
}

// ---------------------------------------------------------------------------
// K2: sort-by-local-row (LDS int atomics = native ds_add_rtn_u32) then
// conflict-free register accumulation + shuffle reduce. NO FP LDS atomics
// (measured R1/R2: CAS retry loop, 568us). 512 threads, 8 waves, 33KB LDS
// -> 4 blocks/CU = 32 waves/CU (R3->R4: 85 -> ~66us). Epilogue: global
// unsafeAtomicAdd (HW global_atomic_add_f32) into z[8192][16], L2-resident.
// FUSED FINALIZE: rows of bucket B are written only by blocks with
// blockIdx.y==B, so a per-bucket done-counter elects the last of the SB2
// chunks (no early-exits) to apply bias+erf+leak for its 64 rows in-kernel.
// Release: __threadfence() before the done increment; the finalizer reads z
// via unsafeAtomicAdd(p, 0.0f) -- an atomic read at the coherence point,
// immune to L1 staleness across XCDs (G16). Removes the finalize dispatch.
__global__ __launch_bounds__(512, 8) void pass2_accum(
    const uint2* __restrict__ e1,
    const int* __restrict__ bcur,
    int* __restrict__ done,             // [NBK] (pre-zeroed)
    const float* __restrict__ srcT,     // [8320][16]
    float* __restrict__ z,              // [N_RES][BATCH] (pre-zeroed)
    const float* __restrict__ state,    // [BATCH][N_RES]
    const float* __restrict__ res_bias,
    const float* __restrict__ in_bias,
    float* __restrict__ out) {          // [BATCH][N_RES]
  int bucket = blockIdx.y;
  int ch = blockIdx.x;
  int tid = threadIdx.x;

  int cnt = bcur[bucket];
  if (cnt > CAP1B) cnt = CAP1B;
  int base = ch * CHUNK2;
  int n = cnt - base;
  if (n < 0) n = 0;
  if (n > CHUNK2) n = CHUNK2;

  __shared__ uint2 stg[CHUNK2];         // 32 KB
  __shared__ int hist[64];
  __shared__ int sbase[65];
  __shared__ int lastflag;
  int wave = tid >> 6, lane = tid & 63;
  if (tid < 64) hist[tid] = 0;
  __syncthreads();

  const uint2* __restrict__ src = e1 + (size_t)bucket * CAP1B + base;
  uint2 ent[8];
  int lp[8];
  unsigned msk = 0;
#pragma unroll
  for (int g = 0; g < 4; ++g) {
    int i = (g * 512 + tid) * 2;        // paired entries, 16B aligned
    int e = g * 2;
    if (i + 1 < n) {
      uint4 q = *(const uint4*)(src + i);
      ent[e]     = make_uint2(q.x, q.y);
      ent[e + 1] = make_uint2(q.z, q.w);
      msk |= 3u << e;
      lp[e]     = atomicAdd(&hist[(ent[e].y >> 14) & 63u], 1);
      lp[e + 1] = atomicAdd(&hist[(ent[e + 1].y >> 14) & 63u], 1);
    } else if (i < n) {
      ent[e] = src[i];
      msk |= 1u << e;
      lp[e] = atomicAdd(&hist[(ent[e].y >> 14) & 63u], 1);
    }
  }
  __syncthreads();
  if (tid < 64) {                       // one wave: 64-bin exclusive scan
    int hh = hist[tid];
    int vv = hh;
#pragma unroll
    for (int d = 1; d < 64; d <<= 1) {
      int t = __shfl_up(vv, d);
      if (lane >= d) vv += t;
    }
    sbase[tid] = vv - hh;
    if (tid == 63) sbase[64] = vv;
  }
  __syncthreads();
#pragma unroll
  for (int e = 0; e < 8; ++e)
    if (msk & (1u << e))
      stg[sbase[(ent[e].y >> 14) & 63u] + lp[e]] = ent[e];
  __syncthreads();

  // Accumulation: wave handles rows wave*8..+7. Per step, 16 entries:
  // 4-lane group (eoff = lane>>2) broadcasts one stg entry and reads one
  // 16B slice (bq = lane&3) of the 64B srcT line; FMA into float4; then
  // shfl_xor{4,8,16,32} reduce; lanes 0..3 -> 16 contiguous global fadds.
  if (n > 0) {
    int eoff = lane >> 2;
    int bq = lane & 3;
    const float4* __restrict__ s4 = (const float4*)srcT;

    for (int rr = wave * 8; rr < wave * 8 + 8; ++rr) {
      int s0 = sbase[rr], s1 = sbase[rr + 1];
      float4 acc = make_float4(0.f, 0.f, 0.f, 0.f);
      for (int i0 = s0; i0 < s1; i0 += 16) {
        int e = i0 + eoff;
        if (e < s1) {
          uint2 ee = stg[e];            // 4-way broadcast, conflict-free
          float vv = __uint_as_float(ee.x);
          float4 s = s4[(int)(ee.y & 16383u) * 4 + bq];
          acc.x += vv * s.x;
          acc.y += vv * s.y;
          acc.z += vv * s.z;
          acc.w += vv * s.w;
        }
      }
#pragma unroll
      for (int m = 4; m <= 32; m <<= 1) {
        acc.x += __shfl_xor(acc.x, m);
        acc.y += __shfl_xor(acc.y, m);
        acc.z += __shfl_xor(acc.z, m);
        acc.w += __shfl_xor(acc.w, m);
      }
      if (lane < 4) {                   // lane == bq 0..3
        float* zp = z + (size_t)(bucket * 64 + rr) * BATCH + lane * 4;
        unsafeAtomicAdd(zp + 0, acc.x);
        unsafeAtomicAdd(zp + 1, acc.y);
        unsafeAtomicAdd(zp + 2, acc.z);
        unsafeAtomicAdd(zp + 3, acc.w);
      }
    }
  }

  // ---- fused finalize: last chunk of this bucket applies bias+erf+leak ----
  __threadfence();                      // release: this block's z adds visible
  __syncthreads();                      // all threads fenced
  if (tid == 0)
    lastflag = (atomicAdd(&done[bucket], 1) == SB2 - 1) ? 1 : 0;
  __syncthreads();
  if (lastflag) {
    __threadfence();                    // acquire side (belt-and-braces)
    for (int i = tid; i < 64 * BATCH; i += 512) {
      int b = i >> 6, rr = i & 63;
      int r = (bucket << 6) + rr;
      float zz = unsafeAtomicAdd(&z[(size_t)r * BATCH + b], 0.0f);  // coherent read
      zz += res_bias[r] + in_bias[r];
      out[b * N_RES + r] =
          (1.0f - LEAK) * state[b * N_RES + r] + LEAK * erff(zz);
    }
  }
}

// ---------------------------------------------------------------------------
__global__ __launch_bounds__(256) void finalize_z(
    const float* __restrict__ z, const float* __restrict__ state,
    const float* __restrict__ res_bias, const float* __restrict__ in_bias,
    float* __restrict__ out) {
  int tid = blockIdx.x * 256 + threadIdx.x;
  if (tid >= BATCH * N_RES) return;
  int b = tid >> 13;
  int r = tid & (N_RES - 1);
  float zz = z[r * 16 + b] + res_bias[r] + in_bias[r];
  out[tid] = (1.0f - LEAK) * state[tid] + LEAK * erff(zz);
}

// ---------------------------------------------------------------------------
// Fallback (small ws): atomic path, correct but slow.
__global__ __launch_bounds__(256) void transpose_nb(
    const float* __restrict__ state, const float* __restrict__ x,
    float* __restrict__ srcT) {
  int tid = blockIdx.x * 256 + threadIdx.x;
  if (tid < N_RES * BATCH) {
    int b = tid >> 13;
    int r = tid & (N_RES - 1);
    srcT[r * BATCH + b] = state[tid];
  }
  if (tid < N_IN * BATCH) {
    int b = tid >> 7;
    int c = tid & (N_IN - 1);
    srcT[(N_RES + c) * BATCH + b] = x[tid];
  }
}

__global__ __launch_bounds__(256) void spmm_atomic(
    const float* __restrict__ vals, const int* __restrict__ rows,
    const int* __restrict__ cols, const float* __restrict__ srcT,
    int col_off, float* __restrict__ zz, int nnz) {
  int i = blockIdx.x * blockDim.x + threadIdx.x;
  if (i >= nnz) return;
  float v = vals[i];
  int r = rows[i];
  int c = cols[i] + col_off;
  const float4* __restrict__ sp = (const float4*)(srcT + c * BATCH);
  float* zr = zz + r * BATCH;
#pragma unroll
  for (int qq = 0; qq < 4; ++qq) {
    float4 s = sp[qq];
    unsafeAtomicAdd(zr + qq * 4 + 0, v * s.x);
    unsafeAtomicAdd(zr + qq * 4 + 1, v * s.y);
    unsafeAtomicAdd(zr + qq * 4 + 2, v * s.z);
    unsafeAtomicAdd(zr + qq * 4 + 3, v * s.w);
  }
}

// ---------------------------------------------------------------------------
extern "C" void kernel_launch(void* const* d_in, const int* in_sizes, int n_in,
                              void* d_out, int out_size, void* d_ws, size_t ws_size,
                              hipStream_t stream) {
  const float* state    = (const float*)d_in[0];
  const float* x        = (const float*)d_in[1];
  const float* res_vals = (const float*)d_in[2];
  const int*   res_rows = (const int*)d_in[3];
  const int*   res_cols = (const int*)d_in[4];
  const float* res_bias = (const float*)d_in[5];
  const float* in_vals  = (const float*)d_in[6];
  const int*   in_rows  = (const int*)d_in[7];
  const int*   in_cols  = (const int*)d_in[8];
  const float* in_bias  = (const float*)d_in[9];

  const int res_nnz = in_sizes[2];
  const int in_nnz  = in_sizes[6];

  char* ws = (char*)d_ws;
  float* srcT = (float*)(ws + OFF_SRCT);
  float* z    = (float*)(ws + OFF_Z);
  float* out = (float*)d_out;

  if (ws_size >= REQ_A) {
    int* bcur = (int*)(ws + OFF_BCUR);
    int* done = bcur + NBK;
    uint2* e1 = (uint2*)(ws + OFF_E1);
    int nbres = (res_nnz + CHUNK1 - 1) / CHUNK1;
    int nbin  = (in_nnz + CHUNK1 - 1) / CHUNK1;
    int nchunks = nbres + nbin;

    hipMemsetAsync(bcur, 0, 2 * NBK * sizeof(int), stream);

    pass1_fused<<<nchunks + TBLK, 256, 0, stream>>>(
        state, x, res_vals, res_rows, res_cols, res_nnz, nbres,
        in_vals, in_rows, in_cols, in_nnz, nchunks, srcT, z, e1, bcur);

    pass2_accum<<<dim3(SB2, NBK), 512, 0, stream>>>(
        e1, bcur, done, srcT, z, state, res_bias, in_bias, out);
  } else {
    hipMemsetAsync(z, 0, N_RES * BATCH * sizeof(float), stream);
    transpose_nb<<<512, 256, 0, stream>>>(state, x, srcT);
    spmm_atomic<<<(res_nnz + 255) / 256, 256, 0, stream>>>(
        res_vals, res_rows, res_cols, srcT, 0, z, res_nnz);
    spmm_atomic<<<(in_nnz + 255) / 256, 256, 0, stream>>>(
        in_vals, in_rows, in_cols, srcT, N_RES, z, in_nnz);
    finalize_z<<<512, 256, 0, stream>>>(z, state, res_bias, in_bias, out);
  }
}

// Round 7
// 216.878 us; speedup vs baseline: 2.5539x; 2.5539x over previous
//
#include <hip/hip_runtime.h>
#include <math.h>

#define N_RES 8192
#define N_IN  128
#define BATCH 16
#define LEAK  0.9f

#define NBK    128     // buckets (row>>6), 64 rows each
#define CAP1B  55296   // per-bucket capacity (avg 53248, sigma~230, +8.9 sigma)
#define CHUNK1 4096    // pass1 entries per block (R5 post-mortem: 2048 doubled
                       //  block count -> per-block fixed costs + shorter e1
                       //  runs; 4096 geometry measured 65-68us vs 77-80us)
#define CHUNK2 4096    // pass2 entries per block (32KB stg, 512 thr -> 4 blocks/CU)
#define SB2    14      // ceil(CAP1B / CHUNK2) chunks per bucket
#define TBLK   128     // transpose blocks appended to pass1 grid

// Entry encoding: y = (row << 14) | col, row 13 bits, col 14 bits (0..8319).
//   bucket = y >> 20 (row>>6); local row rr = (y >> 14) & 63; col = y & 16383.

// ws layout (bytes):
//   srcT @ 0      : [8320][16] f32 transposed state|x   (532,480)
//   bcur @ 1 MiB  : int[128]
//   z    @ 2 MiB  : [N_RES][BATCH] f32                  (524,288)
//   e1   @ 8 MiB  : uint2[NBK][CAP1B]                   (56,623,104)
// (R5: line-padding bcur falsified -- no time change, +11MB HBM writes.)
// (R6: fusing finalize into pass2 falsified -- 430us latency-stall pathology;
//  keep finalize as its own dispatch.)
#define OFF_SRCT 0
#define OFF_BCUR (1u << 20)
#define OFF_Z    (2u << 20)
#define OFF_E1   (8u << 20)
#define REQ_A    ((size_t)OFF_E1 + (size_t)NBK * CAP1B * 8)   // ~62 MiB

// ---------------------------------------------------------------------------
// K1: pass1 binning (blocks [0, nchunks)) + transpose/z-zero (blocks
// [nchunks, +TBLK)). bcur must be zeroed before launch. srcT and z are
// consumed only by pass2/finalize (next dispatches) -> no intra-kernel
// ordering needed for the transpose section.
__global__ __launch_bounds__(256, 4) void pass1_fused(
    const float* __restrict__ state,   // [BATCH][N_RES]
    const float* __restrict__ x,       // [BATCH][N_IN]
    const float* __restrict__ vres, const int* __restrict__ rres,
    const int* __restrict__ cres, int nres, int nbres,
    const float* __restrict__ vin, const int* __restrict__ rin,
    const int* __restrict__ cin, int nin, int nchunks,
    float* __restrict__ srcT,          // [8320][16]
    float* __restrict__ z,             // [N_RES][BATCH] (zeroed here)
    uint2* __restrict__ e1,            // [NBK][CAP1B]
    int* __restrict__ bcur) {          // [NBK] (pre-zeroed)
  int tid = threadIdx.x;

  if (blockIdx.x >= nchunks) {         // ---- transpose + z-zero section ----
    int idx0 = (blockIdx.x - nchunks) * 256 + tid;
    const int stride = TBLK * 256;
    for (int i = idx0; i < N_RES * BATCH; i += stride) {
      int b = i >> 13;
      int r = i & (N_RES - 1);
      srcT[r * BATCH + b] = state[i];
      z[i] = 0.0f;
    }
    for (int i = idx0; i < N_IN * BATCH; i += stride) {
      int b = i >> 7;
      int c = i & (N_IN - 1);
      srcT[(N_RES + c) * BATCH + b] = x[i];
    }
    return;                            // block-uniform; no barriers used here
  }

  // ---- binning section ----
  const float* vals; const int* rows; const int* cols;
  int nnz, col_off, base;
  if (blockIdx.x < nbres) {
    vals = vres; rows = rres; cols = cres; nnz = nres; col_off = 0;
    base = blockIdx.x * CHUNK1;
  } else {
    vals = vin; rows = rin; cols = cin; nnz = nin; col_off = N_RES;
    base = (blockIdx.x - nbres) * CHUNK1;
  }

  __shared__ uint2 stg[CHUNK1];              // 32 KB
  __shared__ int hist[NBK];
  __shared__ int lbase[NBK];
  __shared__ int gbase[NBK];
  __shared__ int wsum[2];
  int wave = tid >> 6, lane = tid & 63;

  if (tid < NBK) hist[tid] = 0;
  __syncthreads();

  int n = nnz - base;
  if (n > CHUNK1) n = CHUNK1;

  uint2 ent[16];
  int lp[16];
  unsigned msk = 0;
#pragma unroll
  for (int g = 0; g < 4; ++g) {
    int i0 = (g * 256 + tid) * 4;            // 16B-aligned vector offset
    if (i0 + 3 < n) {
      int4 r4 = *(const int4*)(rows + base + i0);
      int4 c4 = *(const int4*)(cols + base + i0);
      float4 v4 = *(const float4*)(vals + base + i0);
      int rr_[4] = {r4.x, r4.y, r4.z, r4.w};
      int cc_[4] = {c4.x, c4.y, c4.z, c4.w};
      float vv_[4] = {v4.x, v4.y, v4.z, v4.w};
#pragma unroll
      for (int j = 0; j < 4; ++j) {
        int e = g * 4 + j;
        ent[e] = make_uint2(__float_as_uint(vv_[j]),
                            ((unsigned)rr_[j] << 14) |
                                (unsigned)(cc_[j] + col_off));
        msk |= 1u << e;
        lp[e] = atomicAdd(&hist[rr_[j] >> 6], 1);
      }
    } else {
#pragma unroll
      for (int j = 0; j < 4; ++j) {
        int e = g * 4 + j, i = i0 + j;
        if (i < n) {
          int r = rows[base + i];
          int c = cols[base + i] + col_off;
          float v = vals[base + i];
          ent[e] = make_uint2(__float_as_uint(v),
                              ((unsigned)r << 14) | (unsigned)c);
          msk |= 1u << e;
          lp[e] = atomicAdd(&hist[r >> 6], 1);
        }
      }
    }
  }
  __syncthreads();

  int h = 0, v = 0;
  if (tid < NBK) {                           // waves 0,1 scan 128 bins
    h = hist[tid];
    v = h;
#pragma unroll
    for (int d = 1; d < 64; d <<= 1) {
      int t = __shfl_up(v, d);
      if (lane >= d) v += t;
    }
    if (lane == 63) wsum[wave] = v;
  }
  __syncthreads();
  if (tid < NBK) {
    int off = (wave == 1) ? wsum[0] : 0;
    lbase[tid] = off + v - h;
    gbase[tid] = h ? atomicAdd(&bcur[tid], h) : 0;
  }
  __syncthreads();
#pragma unroll
  for (int e = 0; e < 16; ++e) {
    if (msk & (1u << e)) {
      int b = (int)(ent[e].y >> 20);         // recompute bin from packed row
      stg[lbase[b] + lp[e]] = ent[e];
    }
  }
  __syncthreads();
  for (int i = tid; i < n; i += 256) {
    uint2 ld = stg[i];
    int b = (int)(ld.y >> 20);
    int p = gbase[b] + (i - lbase[b]);
    if (p < CAP1B) e1[(size_t)b * CAP1B + p] = ld;
  }
}

// ---------------------------------------------------------------------------
// K2: EXACT R4 version (proven <=76us). Sort-by-local-row (LDS int atomics =
// native ds_add_rtn_u32) then conflict-free register accumulation + shuffle
// reduce. NO FP LDS atomics (R1/R2: CAS retry loop, 568us). NO fused
// finalize (R6: 430us codegen pathology). 512 threads, 8 waves, 33KB LDS
// -> 4 blocks/CU = 32 waves/CU. Epilogue: global unsafeAtomicAdd (HW
// global_atomic_add_f32) into z[8192][16], L2-resident. Grid: (SB2, NBK).
__global__ __launch_bounds__(512, 8) void pass2_accum(
    const uint2* __restrict__ e1,
    const int* __restrict__ bcur,
    const float* __restrict__ srcT,     // [8320][16]
    float* __restrict__ z) {            // [N_RES][BATCH] (pre-zeroed)
  int bucket = blockIdx.y;
  int ch = blockIdx.x;
  int tid = threadIdx.x;

  int cnt = bcur[bucket];
  if (cnt > CAP1B) cnt = CAP1B;
  int base = ch * CHUNK2;
  if (base >= cnt) return;              // block-uniform early exit
  int n = cnt - base;
  if (n > CHUNK2) n = CHUNK2;

  __shared__ uint2 stg[CHUNK2];         // 32 KB
  __shared__ int hist[64];
  __shared__ int sbase[65];
  int wave = tid >> 6, lane = tid & 63;
  if (tid < 64) hist[tid] = 0;
  __syncthreads();

  const uint2* __restrict__ src = e1 + (size_t)bucket * CAP1B + base;
  uint2 ent[8];
  int lp[8];
  unsigned msk = 0;
#pragma unroll
  for (int g = 0; g < 4; ++g) {
    int i = (g * 512 + tid) * 2;        // paired entries, 16B aligned
    int e = g * 2;
    if (i + 1 < n) {
      uint4 q = *(const uint4*)(src + i);
      ent[e]     = make_uint2(q.x, q.y);
      ent[e + 1] = make_uint2(q.z, q.w);
      msk |= 3u << e;
      lp[e]     = atomicAdd(&hist[(ent[e].y >> 14) & 63u], 1);
      lp[e + 1] = atomicAdd(&hist[(ent[e + 1].y >> 14) & 63u], 1);
    } else if (i < n) {
      ent[e] = src[i];
      msk |= 1u << e;
      lp[e] = atomicAdd(&hist[(ent[e].y >> 14) & 63u], 1);
    }
  }
  __syncthreads();
  if (tid < 64) {                       // one wave: 64-bin exclusive scan
    int hh = hist[tid];
    int vv = hh;
#pragma unroll
    for (int d = 1; d < 64; d <<= 1) {
      int t = __shfl_up(vv, d);
      if (lane >= d) vv += t;
    }
    sbase[tid] = vv - hh;
    if (tid == 63) sbase[64] = vv;
  }
  __syncthreads();
#pragma unroll
  for (int e = 0; e < 8; ++e)
    if (msk & (1u << e))
      stg[sbase[(ent[e].y >> 14) & 63u] + lp[e]] = ent[e];
  __syncthreads();

  // Accumulation: wave handles rows wave*8..+7. Per step, 16 entries:
  // 4-lane group (eoff = lane>>2) broadcasts one stg entry and reads one
  // 16B slice (bq = lane&3) of the 64B srcT line; FMA into float4; then
  // shfl_xor{4,8,16,32} reduce; lanes 0..3 -> 16 contiguous global fadds.
  int eoff = lane >> 2;
  int bq = lane & 3;
  const float4* __restrict__ s4 = (const float4*)srcT;

  for (int rr = wave * 8; rr < wave * 8 + 8; ++rr) {
    int s0 = sbase[rr], s1 = sbase[rr + 1];
    float4 acc = make_float4(0.f, 0.f, 0.f, 0.f);
    for (int i0 = s0; i0 < s1; i0 += 16) {
      int e = i0 + eoff;
      if (e < s1) {
        uint2 ee = stg[e];              // 4-way broadcast, conflict-free
        float vv = __uint_as_float(ee.x);
        float4 s = s4[(int)(ee.y & 16383u) * 4 + bq];
        acc.x += vv * s.x;
        acc.y += vv * s.y;
        acc.z += vv * s.z;
        acc.w += vv * s.w;
      }
    }
#pragma unroll
    for (int m = 4; m <= 32; m <<= 1) {
      acc.x += __shfl_xor(acc.x, m);
      acc.y += __shfl_xor(acc.y, m);
      acc.z += __shfl_xor(acc.z, m);
      acc.w += __shfl_xor(acc.w, m);
    }
    if (lane < 4) {                     // lane == bq 0..3
      float* zp = z + (size_t)(bucket * 64 + rr) * BATCH + lane * 4;
      unsafeAtomicAdd(zp + 0, acc.x);
      unsafeAtomicAdd(zp + 1, acc.y);
      unsafeAtomicAdd(zp + 2, acc.z);
      unsafeAtomicAdd(zp + 3, acc.w);
    }
  }
}

// ---------------------------------------------------------------------------
__global__ __launch_bounds__(256) void finalize_z(
    const float* __restrict__ z, const float* __restrict__ state,
    const float* __restrict__ res_bias, const float* __restrict__ in_bias,
    float* __restrict__ out) {
  int tid = blockIdx.x * 256 + threadIdx.x;
  if (tid >= BATCH * N_RES) return;
  int b = tid >> 13;
  int r = tid & (N_RES - 1);
  float zz = z[r * 16 + b] + res_bias[r] + in_bias[r];
  out[tid] = (1.0f - LEAK) * state[tid] + LEAK * erff(zz);
}

// ---------------------------------------------------------------------------
// Fallback (small ws): atomic path, correct but slow.
__global__ __launch_bounds__(256) void transpose_nb(
    const float* __restrict__ state, const float* __restrict__ x,
    float* __restrict__ srcT) {
  int tid = blockIdx.x * 256 + threadIdx.x;
  if (tid < N_RES * BATCH) {
    int b = tid >> 13;
    int r = tid & (N_RES - 1);
    srcT[r * BATCH + b] = state[tid];
  }
  if (tid < N_IN * BATCH) {
    int b = tid >> 7;
    int c = tid & (N_IN - 1);
    srcT[(N_RES + c) * BATCH + b] = x[tid];
  }
}

__global__ __launch_bounds__(256) void spmm_atomic(
    const float* __restrict__ vals, const int* __restrict__ rows,
    const int* __restrict__ cols, const float* __restrict__ srcT,
    int col_off, float* __restrict__ zz, int nnz) {
  int i = blockIdx.x * blockDim.x + threadIdx.x;
  if (i >= nnz) return;
  float v = vals[i];
  int r = rows[i];
  int c = cols[i] + col_off;
  const float4* __restrict__ sp = (const float4*)(srcT + c * BATCH);
  float* zr = zz + r * BATCH;
#pragma unroll
  for (int qq = 0; qq < 4; ++qq) {
    float4 s = sp[qq];
    unsafeAtomicAdd(zr + qq * 4 + 0, v * s.x);
    unsafeAtomicAdd(zr + qq * 4 + 1, v * s.y);
    unsafeAtomicAdd(zr + qq * 4 + 2, v * s.z);
    unsafeAtomicAdd(zr + qq * 4 + 3, v * s.w);
  }
}

// ---------------------------------------------------------------------------
extern "C" void kernel_launch(void* const* d_in, const int* in_sizes, int n_in,
                              void* d_out, int out_size, void* d_ws, size_t ws_size,
                              hipStream_t stream) {
  const float* state    = (const float*)d_in[0];
  const float* x        = (const float*)d_in[1];
  const float* res_vals = (const float*)d_in[2];
  const int*   res_rows = (const int*)d_in[3];
  const int*   res_cols = (const int*)d_in[4];
  const float* res_bias = (const float*)d_in[5];
  const float* in_vals  = (const float*)d_in[6];
  const int*   in_rows  = (const int*)d_in[7];
  const int*   in_cols  = (const int*)d_in[8];
  const float* in_bias  = (const float*)d_in[9];

  const int res_nnz = in_sizes[2];
  const int in_nnz  = in_sizes[6];

  char* ws = (char*)d_ws;
  float* srcT = (float*)(ws + OFF_SRCT);
  float* z    = (float*)(ws + OFF_Z);
  float* out = (float*)d_out;

  if (ws_size >= REQ_A) {
    int* bcur = (int*)(ws + OFF_BCUR);
    uint2* e1 = (uint2*)(ws + OFF_E1);
    int nbres = (res_nnz + CHUNK1 - 1) / CHUNK1;
    int nbin  = (in_nnz + CHUNK1 - 1) / CHUNK1;
    int nchunks = nbres + nbin;

    hipMemsetAsync(bcur, 0, NBK * sizeof(int), stream);

    pass1_fused<<<nchunks + TBLK, 256, 0, stream>>>(
        state, x, res_vals, res_rows, res_cols, res_nnz, nbres,
        in_vals, in_rows, in_cols, in_nnz, nchunks, srcT, z, e1, bcur);

    pass2_accum<<<dim3(SB2, NBK), 512, 0, stream>>>(e1, bcur, srcT, z);

    finalize_z<<<512, 256, 0, stream>>>(z, state, res_bias, in_bias, out);
  } else {
    hipMemsetAsync(z, 0, N_RES * BATCH * sizeof(float), stream);
    transpose_nb<<<512, 256, 0, stream>>>(state, x, srcT);
    spmm_atomic<<<(res_nnz + 255) / 256, 256, 0, stream>>>(
        res_vals, res_rows, res_cols, srcT, 0, z, res_nnz);
    spmm_atomic<<<(in_nnz + 255) / 256, 256, 0, stream>>>(
        in_vals, in_rows, in_cols, srcT, N_RES, z, in_nnz);
    finalize_z<<<512, 256, 0, stream>>>(z, state, res_bias, in_bias, out);
  }
}